// Round 11
// baseline (262.063 us; speedup 1.0000x reference)
//
#include <hip/hip_runtime.h>
#include <hip/hip_fp16.h>

#define N_NODES 100000
#define N_EDGES 3200000
#define F_IN    128
#define F_HID   32

#define BSHIFT  7
#define BKSZ    128                               // nodes per bucket
#define NBKT    ((N_NODES + BKSZ - 1) / BKSZ)     // 782
#define CAP     4608                              // bucket capacity: mean 4092 + 8 sigma
#define CHUNK   4096                              // edges per partition block
#define NBLK_E  ((N_EDGES + CHUNK - 1) / CHUNK)   // 782
#define RBITS   17                                // row id bits (100000 < 2^17)
#define RMASK   0x1FFFF

// ---------------- coarse partition (fixed-capacity buckets, relative cursors) ----------------
// gcur[] zeroed by hipMemsetAsync; holds per-bucket edge count after k_part.

__global__ __launch_bounds__(512) void k_part(const int* __restrict__ row, const int* __restrict__ col,
                                              int* __restrict__ gcur, unsigned* __restrict__ bkt) {
    __shared__ int hist[NBKT];
    __shared__ int lbase[NBKT];          // local (block) exclusive prefix
    __shared__ int gbase[NBKT];          // global destination base (absolute)
    __shared__ unsigned perm[CHUNK];     // 16 KB: packed words, bucket-major
    __shared__ unsigned short pb[CHUNK]; // 8 KB: bucket id per slot
    __shared__ int wt[8];
    int t = threadIdx.x;
    for (int i = t; i < NBKT; i += 512) hist[i] = 0;
    __syncthreads();

    int e0 = blockIdx.x * CHUNK;
    int n  = min(CHUNK, N_EDGES - e0);
    int r[8], c[8], rk[8];
#pragma unroll
    for (int k = 0; k < 8; k++) {
        int idx = t + k * 512;
        if (idx < n) {
            r[k]  = row[e0 + idx];
            c[k]  = col[e0 + idx];
            rk[k] = atomicAdd(&hist[c[k] >> BSHIFT], 1);   // local rank in bucket
        }
    }
    __syncthreads();

    // block scan: each thread owns 2 consecutive buckets
    {
        int b0 = t * 2;
        int s0 = (b0     < NBKT) ? hist[b0]     : 0;
        int s1 = (b0 + 1 < NBKT) ? hist[b0 + 1] : 0;
        int tsum = s0 + s1;
        int lane = t & 63, wid = t >> 6;
        int incl = tsum;
#pragma unroll
        for (int sh = 1; sh < 64; sh <<= 1) {
            int u = __shfl_up(incl, sh);
            if (lane >= sh) incl += u;
        }
        if (lane == 63) wt[wid] = incl;
        __syncthreads();
        int wpre = 0;
        for (int w = 0; w < wid; w++) wpre += wt[w];
        int excl = wpre + incl - tsum;
        if (b0     < NBKT) lbase[b0]     = excl;
        if (b0 + 1 < NBKT) lbase[b0 + 1] = excl + s0;
    }
    for (int i = t; i < NBKT; i += 512) {
        int h = hist[i];
        gbase[i] = i * CAP + (h ? atomicAdd(&gcur[i], h) : 0);
    }
    __syncthreads();

#pragma unroll
    for (int k = 0; k < 8; k++) {
        int idx = t + k * 512;
        if (idx < n) {
            int b   = c[k] >> BSHIFT;
            int pos = lbase[b] + rk[k];
            perm[pos] = (unsigned)r[k] | ((unsigned)(c[k] & (BKSZ - 1)) << RBITS);
            pb[pos]   = (unsigned short)b;
        }
    }
    __syncthreads();

    for (int i = t; i < n; i += 512) {
        int b = pb[i];
        bkt[gbase[b] + (i - lbase[b])] = perm[i];
    }
}

// ---------------- per-bucket fine sort, IN PLACE (LDS staging), + off/end/dinv ----------------

__global__ __launch_bounds__(1024) void k_bucket(unsigned* __restrict__ bkt,  // in: bkt, out: srt (aliased)
                                                 const int* __restrict__ gcur,
                                                 int* __restrict__ off, int* __restrict__ end,
                                                 float* __restrict__ dinv) {
    __shared__ unsigned stg[CAP];   // 18.4 KB staging
    __shared__ int cnt[BKSZ];
    __shared__ int cur[BKSZ];
    __shared__ int wtot[2];
    int t = threadIdx.x, b = blockIdx.x;
    int s = b * CAP, m = gcur[b];   // gcur holds the bucket count
    if (t < BKSZ) cnt[t] = 0;
    __syncthreads();
    for (int i = t; i < m; i += 1024) {
        unsigned x = bkt[s + i];
        stg[i] = x;
        atomicAdd(&cnt[x >> RBITS], 1);
    }
    __syncthreads();

    int lane = t & 63, wid = t >> 6;
    int v = 0, incl = 0;
    if (t < BKSZ) {
        v = cnt[t];
        incl = v;
        #pragma unroll
        for (int sh = 1; sh < 64; sh <<= 1) {
            int u = __shfl_up(incl, sh);
            if (lane >= sh) incl += u;
        }
        if (lane == 63) wtot[wid] = incl;
    }
    __syncthreads();
    if (t < BKSZ) {
        int wpre = (wid == 1) ? wtot[0] : 0;
        int excl = wpre + incl - v;
        cur[t] = s + excl;
        int g = b * BKSZ + t;
        if (g < N_NODES) {
            off[g]  = s + excl;
            end[g]  = s + excl + v;
            dinv[g] = rsqrtf((float)(v + 1));   // +1 self-loop
        }
    }
    __syncthreads();
    for (int i = t; i < m; i += 1024) {
        unsigned x = stg[i];
        int p = atomicAdd(&cur[x >> RBITS], 1);
        bkt[p] = x & RMASK;   // srt: row ids grouped by dest node
    }
}

// ---------------- h1s = fp16( dinv[r] * (x @ W1)[r] ), 4 feats/thread, ds_read_b128 ----------------

__global__ __launch_bounds__(256) void k_gemm1(const float* __restrict__ x, const float* __restrict__ W1,
                                               const float* __restrict__ dinv, unsigned* __restrict__ h1s) {
    __shared__ float Wlds[F_IN * F_HID];  // 16 KB, [k][f]
    int t = threadIdx.x;
    for (int i = t; i < F_IN * F_HID; i += 256) Wlds[i] = W1[i];
    __syncthreads();

    int gid = blockIdx.x * 256 + t;   // gid = r*8 + f4 ; feats 4f4..4f4+3
    int r = gid >> 3, f4 = gid & 7;
    if (r >= N_NODES) return;

    const float4* x4  = (const float4*)(x + (size_t)r * F_IN);
    const float4* Wl4 = (const float4*)Wlds;   // [(k)*8 + f4]
    float ax = 0.f, ay = 0.f, az = 0.f, aw = 0.f;
#pragma unroll
    for (int k4 = 0; k4 < F_IN / 4; k4++) {
        float4 xv = x4[k4];
        float4 w0 = Wl4[(4 * k4 + 0) * 8 + f4];
        ax += xv.x * w0.x; ay += xv.x * w0.y; az += xv.x * w0.z; aw += xv.x * w0.w;
        float4 w1 = Wl4[(4 * k4 + 1) * 8 + f4];
        ax += xv.y * w1.x; ay += xv.y * w1.y; az += xv.y * w1.z; aw += xv.y * w1.w;
        float4 w2 = Wl4[(4 * k4 + 2) * 8 + f4];
        ax += xv.z * w2.x; ay += xv.z * w2.y; az += xv.z * w2.z; aw += xv.z * w2.w;
        float4 w3 = Wl4[(4 * k4 + 3) * 8 + f4];
        ax += xv.w * w3.x; ay += xv.w * w3.y; az += xv.w * w3.z; aw += xv.w * w3.w;
    }
    float di = dinv[r];
    unsigned p01 = (unsigned)__half_as_ushort(__float2half(di * ax))
                 | ((unsigned)__half_as_ushort(__float2half(di * ay)) << 16);
    unsigned p23 = (unsigned)__half_as_ushort(__float2half(di * az))
                 | ((unsigned)__half_as_ushort(__float2half(di * aw)) << 16);
    ((uint2*)h1s)[(size_t)r * 8 + f4] = make_uint2(p01, p23);
}

// ---------------- conv1: one wave per dest node, uint4 gathers + 2x unroll = 32 edges in flight ----
// lane = q*4 + o : o in [0,4) feat-oct (feats 8o..8o+7), q in [0,16) edge slot.
// h2s4[c*4+j] = dinv[c] * (tanh(dinv[c]*(Σ_nb h1s[r] + h1s[c])) @ W2)[j], slot 3 = 0

__global__ __launch_bounds__(256) void k_conv1(const int* __restrict__ off, const int* __restrict__ end,
                                               const int* __restrict__ srt, const float* __restrict__ dinv,
                                               const unsigned* __restrict__ h1s,
                                               const float* __restrict__ W2, float* __restrict__ h2s4) {
    int wid  = threadIdx.x >> 6;
    int lane = threadIdx.x & 63;
    int c = blockIdx.x * 4 + wid;
    if (c >= N_NODES) return;
    int o  = lane & 3;      // feat-oct
    int q  = lane >> 2;     // edge slot (16 slots)
    int pp = q & 3;         // which feature pair of the oct this lane finalizes
    int fA = 8 * o + 2 * pp, fB = fA + 1;

    float wA0 = W2[fA * 3 + 0], wA1 = W2[fA * 3 + 1], wA2 = W2[fA * 3 + 2];
    float wB0 = W2[fB * 3 + 0], wB1 = W2[fB * 3 + 1], wB2 = W2[fB * 3 + 2];

    const uint4* h1q = (const uint4*)h1s;   // row = 4 uint4
    int b = off[c], e = end[c];

    // two independent accumulator sets -> 32 edges in flight per wave
    __half2 a0 = __float2half2_rn(0.f), a1 = a0, a2 = a0, a3 = a0;
    __half2 b0 = a0, b1 = a0, b2 = a0, b3 = a0;
    int p = b + q;
    for (; p + 16 < e; p += 32) {
        int r0 = srt[p];
        int r1 = srt[p + 16];
        uint4 v0 = h1q[(size_t)r0 * 4 + o];   // 16B/lane, 4 lanes/edge
        uint4 v1 = h1q[(size_t)r1 * 4 + o];
        a0 = __hadd2(a0, *(const __half2*)&v0.x); a1 = __hadd2(a1, *(const __half2*)&v0.y);
        a2 = __hadd2(a2, *(const __half2*)&v0.z); a3 = __hadd2(a3, *(const __half2*)&v0.w);
        b0 = __hadd2(b0, *(const __half2*)&v1.x); b1 = __hadd2(b1, *(const __half2*)&v1.y);
        b2 = __hadd2(b2, *(const __half2*)&v1.z); b3 = __hadd2(b3, *(const __half2*)&v1.w);
    }
    if (p < e) {  // at most one remainder slot per lane (p+16 >= e here)
        int r0 = srt[p];
        uint4 v0 = h1q[(size_t)r0 * 4 + o];
        a0 = __hadd2(a0, *(const __half2*)&v0.x); a1 = __hadd2(a1, *(const __half2*)&v0.y);
        a2 = __hadd2(a2, *(const __half2*)&v0.z); a3 = __hadd2(a3, *(const __half2*)&v0.w);
    }
    a0 = __hadd2(a0, b0); a1 = __hadd2(a1, b1); a2 = __hadd2(a2, b2); a3 = __hadd2(a3, b3);

    // to f32 (8 feature sums), butterfly over the 16 edge slots (lane bits 2..5)
    float f0 = __low2float(a0), f1 = __high2float(a0);
    float f2 = __low2float(a1), f3 = __high2float(a1);
    float f4 = __low2float(a2), f5 = __high2float(a2);
    float f6 = __low2float(a3), f7 = __high2float(a3);
#pragma unroll
    for (int m = 4; m <= 32; m <<= 1) {
        f0 += __shfl_xor(f0, m); f1 += __shfl_xor(f1, m);
        f2 += __shfl_xor(f2, m); f3 += __shfl_xor(f3, m);
        f4 += __shfl_xor(f4, m); f5 += __shfl_xor(f5, m);
        f6 += __shfl_xor(f6, m); f7 += __shfl_xor(f7, m);
    }

    // select this lane's pair; add self term (once per finalized feature: each
    // (o,pp) combo lives on 4 lanes, final 64-lane butterfly x0.25 handles it)
    float vA = (pp == 0) ? f0 : (pp == 1) ? f2 : (pp == 2) ? f4 : f6;
    float vB = (pp == 0) ? f1 : (pp == 1) ? f3 : (pp == 2) ? f5 : f7;
    uint4 sv = h1q[(size_t)c * 4 + o];          // self row (already dinv[c]-scaled)
    __half2 sp = ((const __half2*)&sv)[pp];
    vA += __low2float(sp);
    vB += __high2float(sp);

    float di = dinv[c];
    float hA = tanhf(di * vA);
    float hB = tanhf(di * vB);

    float p0 = hA * wA0 + hB * wB0;
    float p1 = hA * wA1 + hB * wB1;
    float p2 = hA * wA2 + hB * wB2;
#pragma unroll
    for (int m = 1; m <= 32; m <<= 1) {
        p0 += __shfl_xor(p0, m);
        p1 += __shfl_xor(p1, m);
        p2 += __shfl_xor(p2, m);
    }
    if (lane < 4) {
        float vv = (lane == 0) ? p0 : (lane == 1) ? p1 : (lane == 2) ? p2 : 0.0f;
        h2s4[(size_t)c * 4 + lane] = (lane < 3) ? (di * 0.25f) * vv : 0.0f;  // slot 3 = real 0
    }
}

// ---------------- conv2: one wave per dest node, 64 edges in flight (float4 loads) ----------------

__global__ __launch_bounds__(256) void k_conv2(const int* __restrict__ off, const int* __restrict__ end,
                                               const int* __restrict__ srt, const float* __restrict__ dinv,
                                               const float* __restrict__ h2s4, float* __restrict__ out) {
    int wid  = threadIdx.x >> 6;
    int lane = threadIdx.x & 63;
    int c = blockIdx.x * 4 + wid;
    if (c >= N_NODES) return;

    const float4* h2v = (const float4*)h2s4;
    int b = off[c], e = end[c];
    float ax = 0.0f, ay = 0.0f, az = 0.0f;
    for (int p = b + lane; p < e; p += 64) {
        int r = srt[p];
        float4 v = h2v[r];
        ax += v.x; ay += v.y; az += v.z;
    }
#pragma unroll
    for (int m = 1; m <= 32; m <<= 1) {
        ax += __shfl_xor(ax, m);
        ay += __shfl_xor(ay, m);
        az += __shfl_xor(az, m);
    }

    float di = dinv[c];
    if (lane < 3) {
        float a = (lane == 0) ? ax : (lane == 1) ? ay : az;
        out[(size_t)c * 3 + lane] = di * (a + h2s4[(size_t)c * 4 + lane]);
    }
}

// ---------------- launch ----------------

extern "C" void kernel_launch(void* const* d_in, const int* in_sizes, int n_in,
                              void* d_out, int out_size, void* d_ws, size_t ws_size,
                              hipStream_t stream) {
    const float* x   = (const float*)d_in[0];
    const int*   ei  = (const int*)d_in[1];  // [2, E] int32
    const float* W1  = (const float*)d_in[2];
    const float* W2  = (const float*)d_in[3];
    float*       out = (float*)d_out;

    const int* row = ei;
    const int* col = ei + N_EDGES;

    char* ws = (char*)d_ws;
    unsigned* bkt = (unsigned*)ws;
    int*      srt = (int*)ws;                 // alias (in-place after k_bucket)
    char*     p   = ws + 4ull * NBKT * CAP;
    int*      gcur = (int*)p;                 p += 4ull * ((NBKT + 63) & ~63);
    int*      off  = (int*)p;                 p += 4ull * N_NODES;
    int*      end  = (int*)p;                 p += 4ull * N_NODES;
    float*    dinv = (float*)p;               p += 4ull * N_NODES;
    unsigned* h1s  = (unsigned*)p;            p += 64ull * N_NODES;
    float*    h2s4 = (float*)p;

    const int B = 256;
    hipMemsetAsync(gcur, 0, 4ull * NBKT, stream);
    hipLaunchKernelGGL(k_part,   dim3(NBLK_E), dim3(512),  0, stream, row, col, gcur, bkt);
    hipLaunchKernelGGL(k_bucket, dim3(NBKT),   dim3(1024), 0, stream, bkt, gcur, off, end, dinv);
    hipLaunchKernelGGL(k_gemm1,  dim3((N_NODES * 8 + B - 1) / B), dim3(B), 0, stream, x, W1, dinv, h1s);
    hipLaunchKernelGGL(k_conv1,  dim3((N_NODES + 3) / 4), dim3(B), 0, stream,
                       off, end, srt, dinv, h1s, W2, h2s4);
    hipLaunchKernelGGL(k_conv2,  dim3((N_NODES + 3) / 4), dim3(B), 0, stream,
                       off, end, srt, dinv, h2s4, out);
}

// Round 12
// 246.734 us; speedup vs baseline: 1.0621x; 1.0621x over previous
//
#include <hip/hip_runtime.h>
#include <hip/hip_fp16.h>

#define N_NODES 100000
#define N_EDGES 3200000
#define F_IN    128
#define F_HID   32

#define BSHIFT  7
#define BKSZ    128                               // nodes per bucket
#define NBKT    ((N_NODES + BKSZ - 1) / BKSZ)     // 782
#define CAP     4608                              // bucket capacity: mean 4092 + 8 sigma
#define CHUNK   4096                              // edges per partition block
#define NBLK_E  ((N_EDGES + CHUNK - 1) / CHUNK)   // 782
#define RBITS   17                                // row id bits (100000 < 2^17)
#define RMASK   0x1FFFF

// ---------------- coarse partition (fixed-capacity buckets, relative cursors) ----------------
// gcur[] zeroed by hipMemsetAsync; holds per-bucket edge count after k_part.

__global__ __launch_bounds__(512) void k_part(const int* __restrict__ row, const int* __restrict__ col,
                                              int* __restrict__ gcur, unsigned* __restrict__ bkt) {
    __shared__ int hist[NBKT];
    __shared__ int lbase[NBKT];          // local (block) exclusive prefix
    __shared__ int gbase[NBKT];          // global destination base (absolute)
    __shared__ unsigned perm[CHUNK];     // 16 KB: packed words, bucket-major
    __shared__ unsigned short pb[CHUNK]; // 8 KB: bucket id per slot
    __shared__ int wt[8];
    int t = threadIdx.x;
    for (int i = t; i < NBKT; i += 512) hist[i] = 0;
    __syncthreads();

    int e0 = blockIdx.x * CHUNK;
    int n  = min(CHUNK, N_EDGES - e0);
    int r[8], c[8], rk[8];
#pragma unroll
    for (int k = 0; k < 8; k++) {
        int idx = t + k * 512;
        if (idx < n) {
            r[k]  = row[e0 + idx];
            c[k]  = col[e0 + idx];
            rk[k] = atomicAdd(&hist[c[k] >> BSHIFT], 1);   // local rank in bucket
        }
    }
    __syncthreads();

    // block scan: each thread owns 2 consecutive buckets
    {
        int b0 = t * 2;
        int s0 = (b0     < NBKT) ? hist[b0]     : 0;
        int s1 = (b0 + 1 < NBKT) ? hist[b0 + 1] : 0;
        int tsum = s0 + s1;
        int lane = t & 63, wid = t >> 6;
        int incl = tsum;
#pragma unroll
        for (int sh = 1; sh < 64; sh <<= 1) {
            int u = __shfl_up(incl, sh);
            if (lane >= sh) incl += u;
        }
        if (lane == 63) wt[wid] = incl;
        __syncthreads();
        int wpre = 0;
        for (int w = 0; w < wid; w++) wpre += wt[w];
        int excl = wpre + incl - tsum;
        if (b0     < NBKT) lbase[b0]     = excl;
        if (b0 + 1 < NBKT) lbase[b0 + 1] = excl + s0;
    }
    for (int i = t; i < NBKT; i += 512) {
        int h = hist[i];
        gbase[i] = i * CAP + (h ? atomicAdd(&gcur[i], h) : 0);
    }
    __syncthreads();

#pragma unroll
    for (int k = 0; k < 8; k++) {
        int idx = t + k * 512;
        if (idx < n) {
            int b   = c[k] >> BSHIFT;
            int pos = lbase[b] + rk[k];
            perm[pos] = (unsigned)r[k] | ((unsigned)(c[k] & (BKSZ - 1)) << RBITS);
            pb[pos]   = (unsigned short)b;
        }
    }
    __syncthreads();

    for (int i = t; i < n; i += 512) {
        int b = pb[i];
        bkt[gbase[b] + (i - lbase[b])] = perm[i];
    }
}

// ---------------- per-bucket fine sort, IN PLACE (LDS staging), + off/end/dinv ----------------

__global__ __launch_bounds__(1024) void k_bucket(unsigned* __restrict__ bkt,  // in: bkt, out: srt (aliased)
                                                 const int* __restrict__ gcur,
                                                 int* __restrict__ off, int* __restrict__ end,
                                                 float* __restrict__ dinv) {
    __shared__ unsigned stg[CAP];   // 18.4 KB staging
    __shared__ int cnt[BKSZ];
    __shared__ int cur[BKSZ];
    __shared__ int wtot[2];
    int t = threadIdx.x, b = blockIdx.x;
    int s = b * CAP, m = gcur[b];   // gcur holds the bucket count
    if (t < BKSZ) cnt[t] = 0;
    __syncthreads();
    for (int i = t; i < m; i += 1024) {
        unsigned x = bkt[s + i];
        stg[i] = x;
        atomicAdd(&cnt[x >> RBITS], 1);
    }
    __syncthreads();

    int lane = t & 63, wid = t >> 6;
    int v = 0, incl = 0;
    if (t < BKSZ) {
        v = cnt[t];
        incl = v;
        #pragma unroll
        for (int sh = 1; sh < 64; sh <<= 1) {
            int u = __shfl_up(incl, sh);
            if (lane >= sh) incl += u;
        }
        if (lane == 63) wtot[wid] = incl;
    }
    __syncthreads();
    if (t < BKSZ) {
        int wpre = (wid == 1) ? wtot[0] : 0;
        int excl = wpre + incl - v;
        cur[t] = s + excl;
        int g = b * BKSZ + t;
        if (g < N_NODES) {
            off[g]  = s + excl;
            end[g]  = s + excl + v;
            dinv[g] = rsqrtf((float)(v + 1));   // +1 self-loop
        }
    }
    __syncthreads();
    for (int i = t; i < m; i += 1024) {
        unsigned x = stg[i];
        int p = atomicAdd(&cur[x >> RBITS], 1);
        bkt[p] = x & RMASK;   // srt: row ids grouped by dest node
    }
}

// ---------------- h1s = fp16( dinv[r] * (x @ W1)[r] ), 4 feats/thread, ds_read_b128 ----------------

__global__ __launch_bounds__(256) void k_gemm1(const float* __restrict__ x, const float* __restrict__ W1,
                                               const float* __restrict__ dinv, unsigned* __restrict__ h1s) {
    __shared__ float Wlds[F_IN * F_HID];  // 16 KB, [k][f]
    int t = threadIdx.x;
    for (int i = t; i < F_IN * F_HID; i += 256) Wlds[i] = W1[i];
    __syncthreads();

    int gid = blockIdx.x * 256 + t;   // gid = r*8 + f4 ; feats 4f4..4f4+3
    int r = gid >> 3, f4 = gid & 7;
    if (r >= N_NODES) return;

    const float4* x4  = (const float4*)(x + (size_t)r * F_IN);
    const float4* Wl4 = (const float4*)Wlds;   // [(k)*8 + f4]
    float ax = 0.f, ay = 0.f, az = 0.f, aw = 0.f;
#pragma unroll
    for (int k4 = 0; k4 < F_IN / 4; k4++) {
        float4 xv = x4[k4];
        float4 w0 = Wl4[(4 * k4 + 0) * 8 + f4];
        ax += xv.x * w0.x; ay += xv.x * w0.y; az += xv.x * w0.z; aw += xv.x * w0.w;
        float4 w1 = Wl4[(4 * k4 + 1) * 8 + f4];
        ax += xv.y * w1.x; ay += xv.y * w1.y; az += xv.y * w1.z; aw += xv.y * w1.w;
        float4 w2 = Wl4[(4 * k4 + 2) * 8 + f4];
        ax += xv.z * w2.x; ay += xv.z * w2.y; az += xv.z * w2.z; aw += xv.z * w2.w;
        float4 w3 = Wl4[(4 * k4 + 3) * 8 + f4];
        ax += xv.w * w3.x; ay += xv.w * w3.y; az += xv.w * w3.z; aw += xv.w * w3.w;
    }
    float di = dinv[r];
    unsigned p01 = (unsigned)__half_as_ushort(__float2half(di * ax))
                 | ((unsigned)__half_as_ushort(__float2half(di * ay)) << 16);
    unsigned p23 = (unsigned)__half_as_ushort(__float2half(di * az))
                 | ((unsigned)__half_as_ushort(__float2half(di * aw)) << 16);
    ((uint2*)h1s)[(size_t)r * 8 + f4] = make_uint2(p01, p23);
}

// ---------------- conv1: one wave per dest node, uint2 gathers, 2x unroll = 16 edges in flight ----
// R10 structure (known VGPR16/no-spill) + one extra accumulator pair. R11 lesson:
// uint4 + dual-set unroll spilled to LDS (LDS_Block_Size=4096, 200K bank conflicts).
// h2s4[c*4+j] = dinv[c] * (tanh(dinv[c]*(Σ_nb h1s[r] + h1s[c])) @ W2)[j], slot 3 = 0

__global__ __launch_bounds__(256) void k_conv1(const int* __restrict__ off, const int* __restrict__ end,
                                               const int* __restrict__ srt, const float* __restrict__ dinv,
                                               const unsigned* __restrict__ h1s,
                                               const float* __restrict__ W2, float* __restrict__ h2s4) {
    int wid  = threadIdx.x >> 6;
    int lane = threadIdx.x & 63;
    int c = blockIdx.x * 4 + wid;
    if (c >= N_NODES) return;
    int o = lane & 7;       // feat-quad: feats [4o, 4o+4)
    int q = lane >> 3;      // edge slot (8 slots; 2x unroll -> 16 edges in flight)
    int pp = q & 1;         // which feature pair of the quad this lane finalizes
    int fA = 4 * o + 2 * pp, fB = fA + 1;

    float wA0 = W2[fA * 3 + 0], wA1 = W2[fA * 3 + 1], wA2 = W2[fA * 3 + 2];
    float wB0 = W2[fB * 3 + 0], wB1 = W2[fB * 3 + 1], wB2 = W2[fB * 3 + 2];

    int b = off[c], e = end[c];
    __half2 s01a = __float2half2_rn(0.0f), s23a = s01a;
    __half2 s01b = s01a, s23b = s01a;
    const uint2* h1v = (const uint2*)h1s;
    int p = b + q;
    for (; p + 8 < e; p += 16) {
        int r0 = srt[p];                        // two independent srt loads
        int r1 = srt[p + 8];
        uint2 v0 = h1v[(size_t)r0 * 8 + o];     // two gathers in flight per lane
        uint2 v1 = h1v[(size_t)r1 * 8 + o];
        s01a = __hadd2(s01a, *(const __half2*)&v0.x);
        s23a = __hadd2(s23a, *(const __half2*)&v0.y);
        s01b = __hadd2(s01b, *(const __half2*)&v1.x);
        s23b = __hadd2(s23b, *(const __half2*)&v1.y);
    }
    if (p < e) {   // at most one remainder edge per lane (p+8 >= e here)
        int r0 = srt[p];
        uint2 v0 = h1v[(size_t)r0 * 8 + o];
        s01a = __hadd2(s01a, *(const __half2*)&v0.x);
        s23a = __hadd2(s23a, *(const __half2*)&v0.y);
    }
    __half2 s01 = __hadd2(s01a, s01b);
    __half2 s23 = __hadd2(s23a, s23b);

    // to f32, butterfly over the 8 edge slots
    float f0 = __low2float(s01), f1 = __high2float(s01);
    float f2v = __low2float(s23), f3 = __high2float(s23);
#pragma unroll
    for (int m = 8; m <= 32; m <<= 1) {
        f0  += __shfl_xor(f0, m);  f1 += __shfl_xor(f1, m);
        f2v += __shfl_xor(f2v, m); f3 += __shfl_xor(f3, m);
    }

    // self-loop term: added ONCE, after the slot reduction
    uint2 sv = h1v[(size_t)c * 8 + o];          // already dinv[c]-scaled
    f0  += __low2float(*(const __half2*)&sv.x);
    f1  += __high2float(*(const __half2*)&sv.x);
    f2v += __low2float(*(const __half2*)&sv.y);
    f3  += __high2float(*(const __half2*)&sv.y);

    float di = dinv[c];
    float vA = pp ? f2v : f0;
    float vB = pp ? f3  : f1;
    float hA = tanhf(di * vA);
    float hB = tanhf(di * vB);

    // each (o,pp) pair appears on exactly 4 lanes -> full butterfly sums 4x the truth
    float p0 = hA * wA0 + hB * wB0;
    float p1 = hA * wA1 + hB * wB1;
    float p2 = hA * wA2 + hB * wB2;
#pragma unroll
    for (int m = 1; m <= 32; m <<= 1) {
        p0 += __shfl_xor(p0, m);
        p1 += __shfl_xor(p1, m);
        p2 += __shfl_xor(p2, m);
    }
    if (lane < 4) {
        float vv = (lane == 0) ? p0 : (lane == 1) ? p1 : (lane == 2) ? p2 : 0.0f;
        h2s4[(size_t)c * 4 + lane] = (lane < 3) ? (di * 0.25f) * vv : 0.0f;  // slot 3 = real 0
    }
}

// ---------------- conv2: one wave per dest node, 64 edges in flight (float4 loads) ----------------

__global__ __launch_bounds__(256) void k_conv2(const int* __restrict__ off, const int* __restrict__ end,
                                               const int* __restrict__ srt, const float* __restrict__ dinv,
                                               const float* __restrict__ h2s4, float* __restrict__ out) {
    int wid  = threadIdx.x >> 6;
    int lane = threadIdx.x & 63;
    int c = blockIdx.x * 4 + wid;
    if (c >= N_NODES) return;

    const float4* h2v = (const float4*)h2s4;
    int b = off[c], e = end[c];
    float ax = 0.0f, ay = 0.0f, az = 0.0f;
    for (int p = b + lane; p < e; p += 64) {
        int r = srt[p];
        float4 v = h2v[r];
        ax += v.x; ay += v.y; az += v.z;
    }
#pragma unroll
    for (int m = 1; m <= 32; m <<= 1) {
        ax += __shfl_xor(ax, m);
        ay += __shfl_xor(ay, m);
        az += __shfl_xor(az, m);
    }

    float di = dinv[c];
    if (lane < 3) {
        float a = (lane == 0) ? ax : (lane == 1) ? ay : az;
        out[(size_t)c * 3 + lane] = di * (a + h2s4[(size_t)c * 4 + lane]);
    }
}

// ---------------- launch ----------------

extern "C" void kernel_launch(void* const* d_in, const int* in_sizes, int n_in,
                              void* d_out, int out_size, void* d_ws, size_t ws_size,
                              hipStream_t stream) {
    const float* x   = (const float*)d_in[0];
    const int*   ei  = (const int*)d_in[1];  // [2, E] int32
    const float* W1  = (const float*)d_in[2];
    const float* W2  = (const float*)d_in[3];
    float*       out = (float*)d_out;

    const int* row = ei;
    const int* col = ei + N_EDGES;

    char* ws = (char*)d_ws;
    unsigned* bkt = (unsigned*)ws;
    int*      srt = (int*)ws;                 // alias (in-place after k_bucket)
    char*     p   = ws + 4ull * NBKT * CAP;
    int*      gcur = (int*)p;                 p += 4ull * ((NBKT + 63) & ~63);
    int*      off  = (int*)p;                 p += 4ull * N_NODES;
    int*      end  = (int*)p;                 p += 4ull * N_NODES;
    float*    dinv = (float*)p;               p += 4ull * N_NODES;
    unsigned* h1s  = (unsigned*)p;            p += 64ull * N_NODES;
    float*    h2s4 = (float*)p;

    const int B = 256;
    hipMemsetAsync(gcur, 0, 4ull * NBKT, stream);
    hipLaunchKernelGGL(k_part,   dim3(NBLK_E), dim3(512),  0, stream, row, col, gcur, bkt);
    hipLaunchKernelGGL(k_bucket, dim3(NBKT),   dim3(1024), 0, stream, bkt, gcur, off, end, dinv);
    hipLaunchKernelGGL(k_gemm1,  dim3((N_NODES * 8 + B - 1) / B), dim3(B), 0, stream, x, W1, dinv, h1s);
    hipLaunchKernelGGL(k_conv1,  dim3((N_NODES + 3) / 4), dim3(B), 0, stream,
                       off, end, srt, dinv, h1s, W2, h2s4);
    hipLaunchKernelGGL(k_conv2,  dim3((N_NODES + 3) / 4), dim3(B), 0, stream,
                       off, end, srt, dinv, h2s4, out);
}